// Round 12
// baseline (465.543 us; speedup 1.0000x reference)
//
#include <hip/hip_runtime.h>
#include <hip/hip_bf16.h>

#define HW 4096

// ---------------- d_out layout ----------------
// bf16:  [0..1,048,576) q_t [4][4096 n][64 c]   [1,048,576..3,145,728) k_t [2][4][4096 m][64 c]
// fp32:  [1,572,864..1,753,088) wtp    [4,194,304..8,388,608) out1   [8,388,608..12,582,912) out2
// d_ws:  wt_conv bf16 [32][9][256][16] @ 0  (2,359,296 B)
//        wv_bf  bf16 [2][256][256]     @ 2,359,296  (262,144 B)
//        xbf    bf16 [2][4][256][4096] @ 2,621,440  (16,777,216 B)   [ws >= 19.4 MB]
//        cpy    bf16 [4][32][66][66][16] @ 2,621,440 (OVERLAYS dead xbf after attn;
//               17,842,176 B -> needs ws >= 20,463,616)              [ws >= 20.5 MB]
#define KT_OFF   1048576
#define WTP_OFF  1572864
#define O1_OFF   4194304
#define WVB_OFF  1179648        // shorts into d_ws
#define XBF_OFF  1310720        // shorts into d_ws
#define WS_NEED  19398656ull    // bytes: xbf path
#define WS_NEED2 20463616ull    // bytes: conv padded-copy path

typedef short v8s  __attribute__((ext_vector_type(8)));
typedef float v16f __attribute__((ext_vector_type(16)));

#define LSTR 72
#define ZSTR 264
#define CPAD 20
#define PL_ROWS 128
#define PL_SZ  (2 * PL_ROWS * LSTR)
#define XP_SZ  (2 * 256 * LSTR)
#define XLHALF (4 * 66 * CPAD)
#define CPYCH  69696            // shorts per (b,chunk) slab: 66*66*16
#define CPYB   2230272          // shorts per b: 32*CPYCH
#define V5SL   4224             // shorts per conv_v5 x buffer: 4 rows * 66 * 16

__device__ __forceinline__ unsigned short f2b(float f) {
    unsigned u = __float_as_uint(f);
    return (unsigned short)((u + 0x7fffu + ((u >> 16) & 1u)) >> 16);
}
__device__ __forceinline__ unsigned cvt_pk_bf16(float lo, float hi) {
    float2 f2; f2.x = lo; f2.y = hi;
    __hip_bfloat162 h = __float22bfloat162_rn(f2);
    unsigned r;
    __builtin_memcpy(&r, &h, 4);
    return r;
}
__device__ __forceinline__ v8s load8(const unsigned short* p) {
    union { uint2 u[2]; v8s v; } t;
    t.u[0] = *(const uint2*)p;
    t.u[1] = *(const uint2*)(p + 4);
    return t.v;
}

// ---------------- weight prep: proj weights -> [sel][c][co(352)] fp32 ----------------
__global__ __launch_bounds__(256) void wprep_proj(
    const float* __restrict__ wq1, const float* __restrict__ wk1, const float* __restrict__ wv1,
    const float* __restrict__ wq2, const float* __restrict__ wk2, const float* __restrict__ wv2,
    float* __restrict__ wtp) {
    int idx = blockIdx.x * 256 + threadIdx.x;
    if (idx >= 2 * 256 * 352) return;
    int sel = idx / 90112;
    int r   = idx - sel * 90112;
    int c   = r / 352;
    int co  = r - c * 352;
    const float* w; int row;
    if (co < 32)      { w = sel ? wq2 : wq1; row = co; }
    else if (co < 96) { w = sel ? wk2 : wk1; row = co - 32; }
    else              { w = sel ? wv2 : wv1; row = co - 96; }
    wtp[idx] = w[row * 256 + c];
}

// ---------------- weight prep: conv w -> bf16 [chunk][tap][o][ci16] ----------------
__global__ __launch_bounds__(256) void wprep_convw(const float* __restrict__ wcat,
                                                   unsigned short* __restrict__ wt) {
    int i = blockIdx.x * 256 + threadIdx.x;
    if (i >= 32 * 9 * 256 * 16) return;
    const int ci_l = i & 15;
    const int o    = (i >> 4) & 255;
    const int t2   = i >> 12;
    const int tap  = t2 % 9;
    const int chunk = t2 / 9;
    wt[i] = f2b(wcat[((size_t)o * 512 + chunk * 16 + ci_l) * 9 + tap]);
}

// ---------------- weight prep: wv -> bf16 [2][o][c] ----------------
__global__ __launch_bounds__(256) void wprep_wv(const float* __restrict__ wv1,
                                                const float* __restrict__ wv2,
                                                unsigned short* __restrict__ out) {
    int i = blockIdx.x * 256 + threadIdx.x;
    if (i >= 131072) return;
    const float* src = (i < 65536) ? wv1 : wv2;
    out[i] = f2b(src[i & 65535]);
}

// ---------------- x prep: in1|in2 -> bf16 [br][b][c][m] ----------------
__global__ __launch_bounds__(256) void wprep_xbf(const float* __restrict__ x1,
                                                 const float* __restrict__ x2,
                                                 unsigned short* __restrict__ xbf) {
    const size_t e = ((size_t)blockIdx.x * 256 + threadIdx.x) * 8;
    if (e >= 8388608) return;
    const float* src = (e < 4194304) ? (x1 + e) : (x2 + (e - 4194304));
    const float4 a = *(const float4*)src;
    const float4 c = *(const float4*)(src + 4);
    uint4 o;
    o.x = cvt_pk_bf16(a.x, a.y); o.y = cvt_pk_bf16(a.z, a.w);
    o.z = cvt_pk_bf16(c.x, c.y); o.w = cvt_pk_bf16(c.z, c.w);
    *(uint4*)&xbf[e] = o;
}

// ---------------- projections ----------------
__global__ __launch_bounds__(256) void proj_kernel(
    const float* __restrict__ x1, const float* __restrict__ x2,
    const float* __restrict__ bq1, const float* __restrict__ bk1,
    const float* __restrict__ bq2, const float* __restrict__ bk2,
    float* __restrict__ dout) {
    __shared__ __align__(16) float xls[256][64];
    const int tile = blockIdx.x, sel = blockIdx.y, b = blockIdx.z;
    const int n0 = tile * 64;
    const float* xb = (sel ? x2 : x1) + (size_t)b * 256 * HW;

    for (int i = threadIdx.x; i < 4096; i += 256) {
        const int row = i >> 4, c4 = (i & 15) * 4;
        *(float4*)&xls[row][c4] = *(const float4*)(xb + (size_t)row * HW + n0 + c4);
    }
    __syncthreads();

    const int n   = threadIdx.x & 63;
    const int cog = __builtin_amdgcn_readfirstlane(threadIdx.x >> 6);
    const float* bq = sel ? bq2 : bq1;
    const float* bk = sel ? bk2 : bk1;
    const float* wc = dout + WTP_OFF + (size_t)sel * 90112;
    unsigned short* qtg = (unsigned short*)dout + (size_t)b * HW * 64;
    unsigned short* ktg = (unsigned short*)dout + KT_OFF + (size_t)(sel * 4 + b) * HW * 64;

    for (int blk = 0; blk < 3; ++blk) {
        const int co0 = cog * 24 + blk * 8;
        float acc[8];
        const float* brow; int r0; bool isq;
        if (co0 < 32) { r0 = co0;      brow = bq; isq = true;  }
        else          { r0 = co0 - 32; brow = bk; isq = false; }
        #pragma unroll
        for (int k = 0; k < 8; ++k) acc[k] = brow[r0 + k];
        #pragma unroll 4
        for (int c = 0; c < 256; ++c) {
            const float xv = xls[c][n];
            const float4 w0 = *(const float4*)(wc + (size_t)c * 352 + co0);
            const float4 w1 = *(const float4*)(wc + (size_t)c * 352 + co0 + 4);
            acc[0] += xv * w0.x; acc[1] += xv * w0.y; acc[2] += xv * w0.z; acc[3] += xv * w0.w;
            acc[4] += xv * w1.x; acc[5] += xv * w1.y; acc[6] += xv * w1.z; acc[7] += xv * w1.w;
        }
        unsigned pk2[4];
        #pragma unroll
        for (int k = 0; k < 4; ++k) pk2[k] = cvt_pk_bf16(acc[2 * k], acc[2 * k + 1]);
        unsigned short* dst = isq ? (qtg + (size_t)(n0 + n) * 64 + sel * 32 + r0)
                                  : (ktg + (size_t)(n0 + n) * 64 + r0);
        *(uint4*)dst = *(const uint4*)pk2;
    }
}

// ---------------- MFMA attention + fused mix (R10, unchanged) ----------------
template <int USEBF>
__global__ __launch_bounds__(512, 2) void attn_kernel(
    const float* __restrict__ in1, const float* __restrict__ in2,
    const unsigned short* __restrict__ xbf,
    const unsigned short* __restrict__ wvbf,
    const float* __restrict__ bv1, const float* __restrict__ bv2,
    const float* __restrict__ gamma_p,
    float* __restrict__ dout) {
    __shared__ __align__(16) unsigned short smem[PL_SZ + XP_SZ];
    __shared__ float rsums[128][2];
    __shared__ float lfin[128];

    const int bid = blockIdx.x;
    const int g   = bid & 7;
    const int qt  = bid >> 3;
    const int br  = g >> 2, b = g & 3;
    const int t = threadIdx.x;
    const int w = t >> 6, lane = t & 63, h = lane >> 5, l32 = lane & 31;

    const unsigned short* qtg = (const unsigned short*)dout + (size_t)b * HW * 64;
    const unsigned short* ktg = (const unsigned short*)dout + KT_OFF + (size_t)(br * 4 + b) * HW * 64;
    const float* xg = (br ? in2 : in1) + (size_t)b * 256 * HW;
    float* zo = dout + O1_OFF + (size_t)br * 4194304 + (size_t)b * 256 * HW;

    const int msub = (w & 1) * 32;
    const int nsub = (w >> 1) * 32;
    const int cs   = w & 3;
    const int nh   = w >> 2;
    const int koff = h * 8;

    unsigned short* plds = smem;
    unsigned short* xp   = smem + PL_SZ;

    v8s aq[4];
    #pragma unroll
    for (int ks = 0; ks < 4; ++ks)
        aq[ks] = *(const v8s*)(qtg + (size_t)(qt * 128 + nsub + l32) * 64 + ks * 16 + koff);

    const unsigned short* kpt = ktg + (size_t)(msub + l32) * 64 + koff;
    v8s kf[4];
    #pragma unroll
    for (int ks = 0; ks < 4; ++ks)
        kf[ks] = *(const v8s*)(kpt + ks * 16);

    const int m4 = (t & 15) * 4, r0i = t >> 4;
    const float* xgp = xg + (size_t)r0i * HW + m4;
    const unsigned short* xbp = xbf + (size_t)br * 4194304
                              + (size_t)b * 256 * HW + (size_t)r0i * HW + m4;

    uint2 xpk[8];
    if constexpr (USEBF) {
        #pragma unroll
        for (int j = 0; j < 8; ++j) xpk[j] = *(const uint2*)(xbp + (size_t)j * 32 * HW);
    } else {
        float4 xr0[8];
        #pragma unroll
        for (int j = 0; j < 8; ++j) xr0[j] = *(const float4*)(xgp + (size_t)j * 32 * HW);
        #pragma unroll
        for (int j = 0; j < 8; ++j) {
            xpk[j].x = cvt_pk_bf16(xr0[j].x, xr0[j].y);
            xpk[j].y = cvt_pk_bf16(xr0[j].z, xr0[j].w);
        }
    }

    v16f a00, a01, a10, a11;
    #pragma unroll
    for (int i = 0; i < 16; ++i) { a00[i] = 0.f; a01[i] = 0.f; a10[i] = 0.f; a11[i] = 0.f; }
    float racc = 0.f;

    #pragma unroll 1
    for (int mt = 0; mt < 64; ++mt) {
        const int cur = mt & 1;
        v16f s;
        #pragma unroll
        for (int i = 0; i < 16; ++i) s[i] = 0.f;
        #pragma unroll
        for (int ks = 0; ks < 4; ++ks)
            s = __builtin_amdgcn_mfma_f32_32x32x16_bf16(kf[ks], aq[ks], s, 0, 0, 0);
        const int mg = (mt < 63) ? (mt + 1) * 64 : 0;
        #pragma unroll
        for (int ks = 0; ks < 4; ++ks)
            kf[ks] = *(const v8s*)(kpt + (size_t)mg * 64 + ks * 16);
        float4 xr[8];
        if constexpr (!USEBF) {
            #pragma unroll
            for (int j = 0; j < 8; ++j)
                xr[j] = *(const float4*)(xgp + (size_t)j * 32 * HW + mg);
        }
        unsigned short* prow = plds + (size_t)(cur * PL_ROWS + nsub + l32) * LSTR + msub;
        #pragma unroll
        for (int rp = 0; rp < 8; ++rp) {
            const float e0 = __expf(s[2 * rp]);
            const float e1 = __expf(s[2 * rp + 1]);
            racc += e0 + e1;
            const int m0 = ((2 * rp) & 3) + 8 * (rp >> 1) + 4 * h;
            *(unsigned*)&prow[m0] = cvt_pk_bf16(e0, e1);
        }
        {
            unsigned short* xw = xp + (size_t)(cur * 256 + r0i) * LSTR + m4;
            #pragma unroll
            for (int j = 0; j < 8; ++j)
                *(uint2*)(xw + (size_t)j * 32 * LSTR) = xpk[j];
        }
        if constexpr (USEBF) {
            #pragma unroll
            for (int j = 0; j < 8; ++j)
                xpk[j] = *(const uint2*)(xbp + (size_t)j * 32 * HW + mg);
        }
        __syncthreads();
        {
            const unsigned short* xb0 = xp + (size_t)(cur * 256 + cs * 64 + l32) * LSTR;
            const unsigned short* xb1 = xb0 + (size_t)32 * LSTR;
            const unsigned short* pb0 = plds + (size_t)(cur * PL_ROWS + nh * 64 + l32) * LSTR;
            const unsigned short* pb1 = pb0 + (size_t)32 * LSTR;
            #pragma unroll
            for (int ks = 0; ks < 4; ++ks) {
                const int mo = ks * 16 + koff;
                const v8s xa0 = *(const v8s*)(xb0 + mo);
                const v8s xa1 = *(const v8s*)(xb1 + mo);
                const v8s pf0 = *(const v8s*)(pb0 + mo);
                const v8s pf1 = *(const v8s*)(pb1 + mo);
                a00 = __builtin_amdgcn_mfma_f32_32x32x16_bf16(xa0, pf0, a00, 0, 0, 0);
                a01 = __builtin_amdgcn_mfma_f32_32x32x16_bf16(xa0, pf1, a01, 0, 0, 0);
                a10 = __builtin_amdgcn_mfma_f32_32x32x16_bf16(xa1, pf0, a10, 0, 0, 0);
                a11 = __builtin_amdgcn_mfma_f32_32x32x16_bf16(xa1, pf1, a11, 0, 0, 0);
            }
        }
        if constexpr (!USEBF) {
            #pragma unroll
            for (int j = 0; j < 8; ++j) {
                xpk[j].x = cvt_pk_bf16(xr[j].x, xr[j].y);
                xpk[j].y = cvt_pk_bf16(xr[j].z, xr[j].w);
            }
        }
    }
    __syncthreads();
    {
        const float rtot = racc + __shfl_xor(racc, 32);
        if (lane < 32) rsums[nsub + l32][w & 1] = rtot;
    }
    __syncthreads();
    if (t < 128) lfin[t] = 1.0f / (rsums[t][0] + rsums[t][1]);
    __syncthreads();
    const float dn0 = lfin[nh * 64 + l32];
    const float dn1 = lfin[nh * 64 + 32 + l32];
    unsigned short (*zt)[ZSTR] = (unsigned short (*)[ZSTR])smem;
    #pragma unroll
    for (int rp = 0; rp < 8; ++rp) {
        const int r = rp * 2;
        const int c = cs * 64 + (r & 3) + 8 * (r >> 2) + 4 * h;
        const int n0r = nh * 64 + l32, n1r = nh * 64 + 32 + l32;
        *(unsigned*)&zt[n0r][c]      = cvt_pk_bf16(a00[r] * dn0, a00[r + 1] * dn0);
        *(unsigned*)&zt[n1r][c]      = cvt_pk_bf16(a01[r] * dn1, a01[r + 1] * dn1);
        *(unsigned*)&zt[n0r][c + 32] = cvt_pk_bf16(a10[r] * dn0, a10[r + 1] * dn0);
        *(unsigned*)&zt[n1r][c + 32] = cvt_pk_bf16(a11[r] * dn1, a11[r + 1] * dn1);
    }
    __syncthreads();
    const unsigned short* wvb = wvbf + (size_t)br * 65536;
    const float* bvp = br ? bv2 : bv1;
    const float gamma = gamma_p[0];
    const int ob = cs * 64;
    const int ncol = qt * 128 + nh * 64;
    v16f m00, m01, m10, m11;
    #pragma unroll
    for (int i = 0; i < 16; ++i) { m00[i] = 0.f; m01[i] = 0.f; m10[i] = 0.f; m11[i] = 0.f; }
    #pragma unroll
    for (int ks = 0; ks < 16; ++ks) {
        const int k = ks * 16 + koff;
        const v8s aA = *(const v8s*)(wvb + (size_t)(ob + l32) * 256 + k);
        const v8s aB = *(const v8s*)(wvb + (size_t)(ob + 32 + l32) * 256 + k);
        const v8s b0v = *(const v8s*)&zt[nh * 64 + l32][k];
        const v8s b1v = *(const v8s*)&zt[nh * 64 + 32 + l32][k];
        m00 = __builtin_amdgcn_mfma_f32_32x32x16_bf16(aA, b0v, m00, 0, 0, 0);
        m01 = __builtin_amdgcn_mfma_f32_32x32x16_bf16(aA, b1v, m01, 0, 0, 0);
        m10 = __builtin_amdgcn_mfma_f32_32x32x16_bf16(aB, b0v, m10, 0, 0, 0);
        m11 = __builtin_amdgcn_mfma_f32_32x32x16_bf16(aB, b1v, m11, 0, 0, 0);
    }
    #pragma unroll
    for (int r = 0; r < 16; ++r) {
        const int o = ob + (r & 3) + 8 * (r >> 2) + 4 * h;
        const float bvA = bvp[o], bvB = bvp[o + 32];
        const size_t base0 = (size_t)o * HW + ncol;
        const size_t base1 = (size_t)(o + 32) * HW + ncol;
        zo[base0 + l32]      = gamma * (m00[r] + bvA) + xg[base0 + l32];
        zo[base0 + 32 + l32] = gamma * (m01[r] + bvA) + xg[base0 + 32 + l32];
        zo[base1 + l32]      = gamma * (m10[r] + bvB) + xg[base1 + l32];
        zo[base1 + 32 + l32] = gamma * (m11[r] + bvB) + xg[base1 + 32 + l32];
    }
}

// ---------------- cpy_pad: out1/out2 f32 -> padded bf16 [b][chunk][66][66][ci16] ----------------
// (verified R11) Block = one (b, chunk, hp) row. hp 0/65 -> zeros; else transpose [16 ci][64 ww].
__global__ __launch_bounds__(256) void cpy_pad(const float* __restrict__ dsrc,
                                               unsigned short* __restrict__ cpy) {
    __shared__ float xls[16][65];
    const int hp = blockIdx.x, chunk = blockIdx.y, b = blockIdx.z;
    const int t = threadIdx.x;
    unsigned short* crow = cpy + (((size_t)(b * 32 + chunk) * 66 + hp) * 66) * 16;
    if (hp == 0 || hp == 65) {
        if (t < 132) *(uint4*)(crow + t * 8) = make_uint4(0, 0, 0, 0);
        return;
    }
    const int hh = hp - 1;
    const float* src = dsrc + O1_OFF + (size_t)(chunk < 16 ? 0 : 1) * 4194304
                     + (size_t)b * 1048576 + (size_t)((chunk & 15) * 16) * HW + (size_t)hh * 64;
    {
        const int ci = t >> 6, ww = t & 63;
        #pragma unroll
        for (int j = 0; j < 4; ++j)
            xls[ci + 4 * j][ww] = src[(size_t)(ci + 4 * j) * HW + ww];
    }
    __syncthreads();
    {
        const int wwp = t >> 2, q = t & 3;
        uint2 pk;
        pk.x = cvt_pk_bf16(xls[q * 4 + 0][wwp], xls[q * 4 + 1][wwp]);
        pk.y = cvt_pk_bf16(xls[q * 4 + 2][wwp], xls[q * 4 + 3][wwp]);
        *(uint2*)(crow + (size_t)(wwp + 1) * 16 + q * 4) = pk;
    }
    if (t < 4) {
        unsigned short* p = crow + (size_t)(t >> 1) * 65 * 16 + (t & 1) * 8;
        *(uint4*)p = make_uint4(0, 0, 0, 0);
    }
}

// ---------------- conv_v5: LDS x-tile (shared, 3x tap reuse) + direct-global weights ----------------
// 1024 blocks (XCD-swizzled): ot 0..7 (32-o), pt 0..31 (2 rows), b. 4 waves (px-split).
// Per chunk: contiguous 8.4KB x memcpy->LDS (double-buffered, 1 barrier), 9 wf b128 from
// global (all waves same addrs -> L1), 9 b128 LDS B-frags, 9 MFMA.
__global__ __launch_bounds__(256, 4) void conv_v5(
    const unsigned short* __restrict__ wt,
    const unsigned short* __restrict__ cpy,
    const float* __restrict__ bn_scale, const float* __restrict__ bn_bias,
    const float* __restrict__ bn_mean,  const float* __restrict__ bn_var,
    float* __restrict__ dout) {
    __shared__ __align__(16) unsigned short xl[2][V5SL];   // 16,896 B

    const int bid = blockIdx.x;                      // 0..1023
    const int lin = (bid & 7) * 128 + (bid >> 3);    // bijective XCD-localized id
    const int ot  = lin & 7;                         // 32-o slice
    const int g   = lin >> 3;                        // 0..127
    const int pt  = g & 31, b = g >> 5;
    const int h0  = pt * 2;                          // output rows h0, h0+1
    const int t   = threadIdx.x;
    const int w   = t >> 6, lane = t & 63, h = lane >> 5, l32 = lane & 31;
    const int px  = w * 32 + l32;                    // 0..127
    const int r0  = px >> 6, c0 = px & 63;

    // x source: padded rows h0..h0+3 of (b,chunk) = contiguous 4224 shorts
    const unsigned short* cb = cpy + (size_t)b * CPYB + (size_t)h0 * 66 * 16;
    const unsigned short* wb = wt + (size_t)(ot * 32 + l32) * 16 + h * 8;

    v16f acc;
    #pragma unroll
    for (int i = 0; i < 16; ++i) acc[i] = 0.f;

    // prologue: stage chunk 0 x into regs (528 uint4 over 256 threads)
    uint4 xs[3]; bool xv[3];
    #pragma unroll
    for (int j = 0; j < 3; ++j) {
        const int idx = j * 256 + t;
        xv[j] = idx < 528;
        if (xv[j]) xs[j] = *(const uint4*)(cb + (size_t)idx * 8);
    }

    #pragma unroll 1
    for (int chunk = 0; chunk < 32; ++chunk) {
        const int cur = chunk & 1;
        // write staged x -> LDS[cur]
        #pragma unroll
        for (int j = 0; j < 3; ++j)
            if (xv[j]) *(uint4*)&xl[cur][(size_t)(j * 256 + t) * 8] = xs[j];
        // weight A-frags for THIS chunk (consumed after barrier; latency hides under it)
        v8s wf[9];
        {
            const unsigned short* wc = wb + (size_t)chunk * 36864;
            #pragma unroll
            for (int tap = 0; tap < 9; ++tap)
                wf[tap] = *(const v8s*)(wc + (size_t)tap * 4096);
        }
        // prefetch next chunk's x
        if (chunk < 31) {
            const unsigned short* cn = cb + (size_t)(chunk + 1) * CPYCH;
            #pragma unroll
            for (int j = 0; j < 3; ++j)
                if (xv[j]) xs[j] = *(const uint4*)(cn + (size_t)(j * 256 + t) * 8);
        }
        __syncthreads();         // LDS[cur] visible; chunk-2 reads drained (R7 proof)
        // 9 taps: B-frag from LDS[cur], A-frag from regs
        #pragma unroll
        for (int dy = 0; dy < 3; ++dy) {
            #pragma unroll
            for (int dx = 0; dx < 3; ++dx) {
                const v8s bf = *(const v8s*)&xl[cur][(size_t)((r0 + dy) * 66 + c0 + dx) * 16 + h * 8];
                acc = __builtin_amdgcn_mfma_f32_32x32x16_bf16(wf[dy * 3 + dx], bf, acc, 0, 0, 0);
            }
        }
    }
    // epilogue: BN + ReLU (mapping verified by conv_bf pass in R11)
    const size_t gp = (size_t)(h0 + r0) * 64 + c0;
    #pragma unroll
    for (int r = 0; r < 16; ++r) {
        const int o_g = ot * 32 + (r & 3) + 8 * (r >> 2) + 4 * h;
        const float iv = bn_scale[o_g] * __frsqrt_rn(bn_var[o_g] + 1e-5f);
        const float ad = bn_bias[o_g] - bn_mean[o_g] * iv;
        float v = acc[r] * iv + ad;
        v = v > 0.f ? v : 0.f;
        dout[((size_t)b * 256 + o_g) * HW + gp] = v;
    }
}

// ---------------- conv v3 fallback (unchanged, for small ws) ----------------
__global__ __launch_bounds__(256) void conv_kernel(
    const unsigned short* __restrict__ wt,
    const float* __restrict__ bn_scale, const float* __restrict__ bn_bias,
    const float* __restrict__ bn_mean,  const float* __restrict__ bn_var,
    float* __restrict__ dout) {
    __shared__ __align__(16) unsigned short xl[2][4][66][CPAD];
    __shared__ __align__(16) unsigned short wl[2][9][64][CPAD];

    const int bid = blockIdx.x;
    const int xcd = bid & 7, j = bid >> 3;
    const int G   = xcd * 16 + (j >> 2);
    const int ot  = j & 3;
    const int pt  = G & 31;
    const int b   = G >> 5;
    const int h0 = pt * 2;
    const int t  = threadIdx.x;
    const int w  = t >> 6, lane = t & 63, h = lane >> 5, l32 = lane & 31;
    const int osub = (w & 1) * 32;
    const int ps0  = (w >> 1) * 64;

    int ldsoff[9], srcoff[9]; bool valid[9], inb[9];
    #pragma unroll
    for (int k = 0; k < 9; ++k) {
        const int i = t + k * 256;
        valid[k] = i < 2112;
        const int col = i % 66, rem = i / 66;
        const int row = rem & 3, cp = rem >> 2;
        const int hh = h0 + row - 1, ww = col - 1;
        inb[k] = (hh >= 0 && hh < 64 && ww >= 0 && ww < 64);
        srcoff[k] = 2 * cp * HW + (inb[k] ? hh * 64 + ww : 0);
        ldsoff[k] = (row * 66 + col) * CPAD + 2 * cp;
    }
    unsigned short* xlf = &xl[0][0][0][0];

    float inv[16], add[16];
    #pragma unroll
    for (int r = 0; r < 16; ++r) {
        const int o_g = ot * 64 + osub + (r & 3) + 8 * (r >> 2) + 4 * h;
        const float iv = bn_scale[o_g] * __frsqrt_rn(bn_var[o_g] + 1e-5f);
        inv[r] = iv;
        add[r] = bn_bias[o_g] - bn_mean[o_g] * iv;
    }

    v16f acc0, acc1;
    #pragma unroll
    for (int i = 0; i < 16; ++i) { acc0[i] = 0.f; acc1[i] = 0.f; }

    const float* bsrc = dout + O1_OFF + (size_t)b * 1048576;
    const unsigned short* wbase = wt + (size_t)(ot * 64) * 16;

    float xv0[9], xv1[9];
    uint2 wr[9];
    {
        const float* src = bsrc;
        #pragma unroll
        for (int k = 0; k < 9; ++k) {
            xv0[k] = 0.f; xv1[k] = 0.f;
            if (valid[k] && inb[k]) {
                const float* p = src + srcoff[k];
                xv0[k] = p[0]; xv1[k] = p[HW];
            }
        }
        #pragma unroll
        for (int u9 = 0; u9 < 9; ++u9) {
            const int u = t + u9 * 256;
            const int tap = u >> 8, rem2 = u & 255;
            const int o = rem2 >> 2, q = rem2 & 3;
            wr[u9] = *(const uint2*)(wbase + ((size_t)tap * 256 + o) * 16 + q * 4);
        }
    }

    #pragma unroll 1
    for (int chunk = 0; chunk < 32; ++chunk) {
        const int cur = chunk & 1;
        #pragma unroll
        for (int k = 0; k < 9; ++k)
            if (valid[k])
                *(unsigned*)&xlf[cur * XLHALF + ldsoff[k]] = cvt_pk_bf16(xv0[k], xv1[k]);
        #pragma unroll
        for (int u9 = 0; u9 < 9; ++u9) {
            const int u = t + u9 * 256;
            const int tap = u >> 8, rem2 = u & 255;
            const int o = rem2 >> 2, q = rem2 & 3;
            *(uint2*)&wl[cur][tap][o][q * 4] = wr[u9];
        }
        if (chunk < 31) {
            const int cn = chunk + 1;
            const float* src = bsrc + (size_t)(cn < 16 ? 0 : 1) * 4194304
                             + (size_t)((cn & 15) * 16) * HW;
            #pragma unroll
            for (int k = 0; k < 9; ++k) {
                xv0[k] = 0.f; xv1[k] = 0.f;
                if (valid[k] && inb[k]) {
                    const float* p = src + srcoff[k];
                    xv0[k] = p[0]; xv1[k] = p[HW];
                }
            }
            const unsigned short* wsl = wbase + (size_t)cn * 36864;
            #pragma unroll
            for (int u9 = 0; u9 < 9; ++u9) {
                const int u = t + u9 * 256;
                const int tap = u >> 8, rem2 = u & 255;
                const int o = rem2 >> 2, q = rem2 & 3;
                wr[u9] = *(const uint2*)(wsl + ((size_t)tap * 256 + o) * 16 + q * 4);
            }
        }
        __syncthreads();
        #pragma unroll
        for (int dy = 0; dy < 3; ++dy) {
            #pragma unroll
            for (int dx = 0; dx < 3; ++dx) {
                const v8s af = load8(&wl[cur][dy * 3 + dx][osub + l32][h * 8]);
                const int n0 = ps0 + l32, n1 = ps0 + 32 + l32;
                const v8s b0 = load8(&xl[cur][(n0 >> 6) + dy][(n0 & 63) + dx][h * 8]);
                const v8s b1 = load8(&xl[cur][(n1 >> 6) + dy][(n1 & 63) + dx][h * 8]);
                acc0 = __builtin_amdgcn_mfma_f32_32x32x16_bf16(af, b0, acc0, 0, 0, 0);
                acc1 = __builtin_amdgcn_mfma_f32_32x32x16_bf16(af, b1, acc1, 0, 0, 0);
            }
        }
    }
    const int px0 = ps0 + l32, px1 = ps0 + 32 + l32;
    const size_t gpx0 = (size_t)(h0 + (px0 >> 6)) * 64 + (px0 & 63);
    const size_t gpx1 = (size_t)(h0 + (px1 >> 6)) * 64 + (px1 & 63);
    #pragma unroll
    for (int r = 0; r < 16; ++r) {
        const int o_g = ot * 64 + osub + (r & 3) + 8 * (r >> 2) + 4 * h;
        const size_t obase = ((size_t)b * 256 + o_g) * HW;
        float v0 = acc0[r] * inv[r] + add[r];
        float v1 = acc1[r] * inv[r] + add[r];
        v0 = v0 > 0.f ? v0 : 0.f;
        v1 = v1 > 0.f ? v1 : 0.f;
        dout[obase + gpx0] = v0;
        dout[obase + gpx1] = v1;
    }
}

extern "C" void kernel_launch(void* const* d_in, const int* in_sizes, int n_in,
                              void* d_out, int out_size, void* d_ws, size_t ws_size,
                              hipStream_t stream) {
    (void)in_sizes; (void)n_in; (void)out_size;
    const float* x1   = (const float*)d_in[0];
    const float* x2   = (const float*)d_in[1];
    const float* wq1  = (const float*)d_in[2];
    const float* bq1  = (const float*)d_in[3];
    const float* wk1  = (const float*)d_in[4];
    const float* bk1  = (const float*)d_in[5];
    const float* wv1  = (const float*)d_in[6];
    const float* bv1  = (const float*)d_in[7];
    const float* wq2  = (const float*)d_in[8];
    const float* bq2  = (const float*)d_in[9];
    const float* wk2  = (const float*)d_in[10];
    const float* bk2  = (const float*)d_in[11];
    const float* wv2  = (const float*)d_in[12];
    const float* bv2  = (const float*)d_in[13];
    const float* gma  = (const float*)d_in[14];
    const float* wcat = (const float*)d_in[15];
    const float* bns  = (const float*)d_in[16];
    const float* bnb  = (const float*)d_in[17];
    const float* bnm  = (const float*)d_in[18];
    const float* bnv  = (const float*)d_in[19];

    float* out = (float*)d_out;
    unsigned short* wtc = (unsigned short*)d_ws;
    unsigned short* wvb = wtc + WVB_OFF;
    unsigned short* xbf = wtc + XBF_OFF;             // xbf; cpy overlays it post-attn
    const bool use_bf  = ws_size >= WS_NEED;
    const bool use_cvb = ws_size >= WS_NEED2;        // implies use_bf

    wprep_proj<<<704, 256, 0, stream>>>(wq1, wk1, wv1, wq2, wk2, wv2, out + WTP_OFF);
    wprep_convw<<<4608, 256, 0, stream>>>(wcat, wtc);
    wprep_wv<<<512, 256, 0, stream>>>(wv1, wv2, wvb);
    if (use_bf) wprep_xbf<<<4096, 256, 0, stream>>>(x1, x2, xbf);
    proj_kernel<<<dim3(64, 2, 4), 256, 0, stream>>>(x1, x2, bq1, bk1, bq2, bk2, out);
    if (use_bf)
        attn_kernel<1><<<256, 512, 0, stream>>>(x1, x2, xbf, wvb, bv1, bv2, gma, out);
    else
        attn_kernel<0><<<256, 512, 0, stream>>>(x1, x2, xbf, wvb, bv1, bv2, gma, out);
    if (use_cvb) {
        cpy_pad<<<dim3(66, 32, 4), 256, 0, stream>>>(out, xbf);
        conv_v5<<<1024, 256, 0, stream>>>(wtc, xbf, bns, bnb, bnm, bnv, out);
    } else {
        conv_kernel<<<512, 256, 0, stream>>>(wtc, bns, bnb, bnm, bnv, out);
    }
}

// Round 13
// 400.233 us; speedup vs baseline: 1.1632x; 1.1632x over previous
//
#include <hip/hip_runtime.h>
#include <hip/hip_bf16.h>

#define HW 4096

// ---------------- d_out layout ----------------
// bf16:  [0..1,048,576) q_t [4][4096 n][64 c]   [1,048,576..3,145,728) k_t [2][4][4096 m][64 c]
// fp32:  [1,572,864..1,753,088) wtp    [4,194,304..8,388,608) out1   [8,388,608..12,582,912) out2
// d_ws:  wt_conv bf16 [32][9][256][16] @ 0  (2,359,296 B)
//        wv_bf  bf16 [2][256][256]     @ 2,359,296  (262,144 B)
//        xbf    bf16 [2][4][256][4096] @ 2,621,440  (16,777,216 B)   [ws >= 19.4 MB]
//        cpy    bf16 [4][32][66][66][16] @ 2,621,440 (OVERLAYS dead xbf after attn;
//               17,842,176 B -> needs ws >= 20,463,616)              [ws >= 20.5 MB]
#define KT_OFF   1048576
#define WTP_OFF  1572864
#define O1_OFF   4194304
#define WVB_OFF  1179648        // shorts into d_ws
#define XBF_OFF  1310720        // shorts into d_ws
#define WS_NEED  19398656ull    // bytes: xbf path
#define WS_NEED2 20463616ull    // bytes: conv padded-copy path

typedef short v8s  __attribute__((ext_vector_type(8)));
typedef float v16f __attribute__((ext_vector_type(16)));

#define LSTR 72
#define ZSTR 264
#define CPAD 20
#define PL_ROWS 128
#define PL_SZ  (2 * PL_ROWS * LSTR)
#define XP_SZ  (2 * 256 * LSTR)
#define XLHALF (4 * 66 * CPAD)
#define CPYCH  69696            // shorts per (b,chunk) slab: 66*66*16
#define CPYB   2230272          // shorts per b: 32*CPYCH

__device__ __forceinline__ unsigned short f2b(float f) {
    unsigned u = __float_as_uint(f);
    return (unsigned short)((u + 0x7fffu + ((u >> 16) & 1u)) >> 16);
}
__device__ __forceinline__ unsigned cvt_pk_bf16(float lo, float hi) {
    float2 f2; f2.x = lo; f2.y = hi;
    __hip_bfloat162 h = __float22bfloat162_rn(f2);
    unsigned r;
    __builtin_memcpy(&r, &h, 4);
    return r;
}
__device__ __forceinline__ v8s load8(const unsigned short* p) {
    union { uint2 u[2]; v8s v; } t;
    t.u[0] = *(const uint2*)p;
    t.u[1] = *(const uint2*)(p + 4);
    return t.v;
}

// ---------------- weight prep: proj weights -> [sel][c][co(352)] fp32 ----------------
__global__ __launch_bounds__(256) void wprep_proj(
    const float* __restrict__ wq1, const float* __restrict__ wk1, const float* __restrict__ wv1,
    const float* __restrict__ wq2, const float* __restrict__ wk2, const float* __restrict__ wv2,
    float* __restrict__ wtp) {
    int idx = blockIdx.x * 256 + threadIdx.x;
    if (idx >= 2 * 256 * 352) return;
    int sel = idx / 90112;
    int r   = idx - sel * 90112;
    int c   = r / 352;
    int co  = r - c * 352;
    const float* w; int row;
    if (co < 32)      { w = sel ? wq2 : wq1; row = co; }
    else if (co < 96) { w = sel ? wk2 : wk1; row = co - 32; }
    else              { w = sel ? wv2 : wv1; row = co - 96; }
    wtp[idx] = w[row * 256 + c];
}

// ---------------- weight prep: conv w -> bf16 [chunk][tap][o][ci16] ----------------
__global__ __launch_bounds__(256) void wprep_convw(const float* __restrict__ wcat,
                                                   unsigned short* __restrict__ wt) {
    int i = blockIdx.x * 256 + threadIdx.x;
    if (i >= 32 * 9 * 256 * 16) return;
    const int ci_l = i & 15;
    const int o    = (i >> 4) & 255;
    const int t2   = i >> 12;
    const int tap  = t2 % 9;
    const int chunk = t2 / 9;
    wt[i] = f2b(wcat[((size_t)o * 512 + chunk * 16 + ci_l) * 9 + tap]);
}

// ---------------- weight prep: wv -> bf16 [2][o][c] ----------------
__global__ __launch_bounds__(256) void wprep_wv(const float* __restrict__ wv1,
                                                const float* __restrict__ wv2,
                                                unsigned short* __restrict__ out) {
    int i = blockIdx.x * 256 + threadIdx.x;
    if (i >= 131072) return;
    const float* src = (i < 65536) ? wv1 : wv2;
    out[i] = f2b(src[i & 65535]);
}

// ---------------- x prep: in1|in2 -> bf16 [br][b][c][m] ----------------
__global__ __launch_bounds__(256) void wprep_xbf(const float* __restrict__ x1,
                                                 const float* __restrict__ x2,
                                                 unsigned short* __restrict__ xbf) {
    const size_t e = ((size_t)blockIdx.x * 256 + threadIdx.x) * 8;
    if (e >= 8388608) return;
    const float* src = (e < 4194304) ? (x1 + e) : (x2 + (e - 4194304));
    const float4 a = *(const float4*)src;
    const float4 c = *(const float4*)(src + 4);
    uint4 o;
    o.x = cvt_pk_bf16(a.x, a.y); o.y = cvt_pk_bf16(a.z, a.w);
    o.z = cvt_pk_bf16(c.x, c.y); o.w = cvt_pk_bf16(c.z, c.w);
    *(uint4*)&xbf[e] = o;
}

// ---------------- projections ----------------
__global__ __launch_bounds__(256) void proj_kernel(
    const float* __restrict__ x1, const float* __restrict__ x2,
    const float* __restrict__ bq1, const float* __restrict__ bk1,
    const float* __restrict__ bq2, const float* __restrict__ bk2,
    float* __restrict__ dout) {
    __shared__ __align__(16) float xls[256][64];
    const int tile = blockIdx.x, sel = blockIdx.y, b = blockIdx.z;
    const int n0 = tile * 64;
    const float* xb = (sel ? x2 : x1) + (size_t)b * 256 * HW;

    for (int i = threadIdx.x; i < 4096; i += 256) {
        const int row = i >> 4, c4 = (i & 15) * 4;
        *(float4*)&xls[row][c4] = *(const float4*)(xb + (size_t)row * HW + n0 + c4);
    }
    __syncthreads();

    const int n   = threadIdx.x & 63;
    const int cog = __builtin_amdgcn_readfirstlane(threadIdx.x >> 6);
    const float* bq = sel ? bq2 : bq1;
    const float* bk = sel ? bk2 : bk1;
    const float* wc = dout + WTP_OFF + (size_t)sel * 90112;
    unsigned short* qtg = (unsigned short*)dout + (size_t)b * HW * 64;
    unsigned short* ktg = (unsigned short*)dout + KT_OFF + (size_t)(sel * 4 + b) * HW * 64;

    for (int blk = 0; blk < 3; ++blk) {
        const int co0 = cog * 24 + blk * 8;
        float acc[8];
        const float* brow; int r0; bool isq;
        if (co0 < 32) { r0 = co0;      brow = bq; isq = true;  }
        else          { r0 = co0 - 32; brow = bk; isq = false; }
        #pragma unroll
        for (int k = 0; k < 8; ++k) acc[k] = brow[r0 + k];
        #pragma unroll 4
        for (int c = 0; c < 256; ++c) {
            const float xv = xls[c][n];
            const float4 w0 = *(const float4*)(wc + (size_t)c * 352 + co0);
            const float4 w1 = *(const float4*)(wc + (size_t)c * 352 + co0 + 4);
            acc[0] += xv * w0.x; acc[1] += xv * w0.y; acc[2] += xv * w0.z; acc[3] += xv * w0.w;
            acc[4] += xv * w1.x; acc[5] += xv * w1.y; acc[6] += xv * w1.z; acc[7] += xv * w1.w;
        }
        unsigned pk2[4];
        #pragma unroll
        for (int k = 0; k < 4; ++k) pk2[k] = cvt_pk_bf16(acc[2 * k], acc[2 * k + 1]);
        unsigned short* dst = isq ? (qtg + (size_t)(n0 + n) * 64 + sel * 32 + r0)
                                  : (ktg + (size_t)(n0 + n) * 64 + r0);
        *(uint4*)dst = *(const uint4*)pk2;
    }
}

// ---------------- MFMA attention + fused mix (R10, unchanged) ----------------
template <int USEBF>
__global__ __launch_bounds__(512, 2) void attn_kernel(
    const float* __restrict__ in1, const float* __restrict__ in2,
    const unsigned short* __restrict__ xbf,
    const unsigned short* __restrict__ wvbf,
    const float* __restrict__ bv1, const float* __restrict__ bv2,
    const float* __restrict__ gamma_p,
    float* __restrict__ dout) {
    __shared__ __align__(16) unsigned short smem[PL_SZ + XP_SZ];
    __shared__ float rsums[128][2];
    __shared__ float lfin[128];

    const int bid = blockIdx.x;
    const int g   = bid & 7;
    const int qt  = bid >> 3;
    const int br  = g >> 2, b = g & 3;
    const int t = threadIdx.x;
    const int w = t >> 6, lane = t & 63, h = lane >> 5, l32 = lane & 31;

    const unsigned short* qtg = (const unsigned short*)dout + (size_t)b * HW * 64;
    const unsigned short* ktg = (const unsigned short*)dout + KT_OFF + (size_t)(br * 4 + b) * HW * 64;
    const float* xg = (br ? in2 : in1) + (size_t)b * 256 * HW;
    float* zo = dout + O1_OFF + (size_t)br * 4194304 + (size_t)b * 256 * HW;

    const int msub = (w & 1) * 32;
    const int nsub = (w >> 1) * 32;
    const int cs   = w & 3;
    const int nh   = w >> 2;
    const int koff = h * 8;

    unsigned short* plds = smem;
    unsigned short* xp   = smem + PL_SZ;

    v8s aq[4];
    #pragma unroll
    for (int ks = 0; ks < 4; ++ks)
        aq[ks] = *(const v8s*)(qtg + (size_t)(qt * 128 + nsub + l32) * 64 + ks * 16 + koff);

    const unsigned short* kpt = ktg + (size_t)(msub + l32) * 64 + koff;
    v8s kf[4];
    #pragma unroll
    for (int ks = 0; ks < 4; ++ks)
        kf[ks] = *(const v8s*)(kpt + ks * 16);

    const int m4 = (t & 15) * 4, r0i = t >> 4;
    const float* xgp = xg + (size_t)r0i * HW + m4;
    const unsigned short* xbp = xbf + (size_t)br * 4194304
                              + (size_t)b * 256 * HW + (size_t)r0i * HW + m4;

    uint2 xpk[8];
    if constexpr (USEBF) {
        #pragma unroll
        for (int j = 0; j < 8; ++j) xpk[j] = *(const uint2*)(xbp + (size_t)j * 32 * HW);
    } else {
        float4 xr0[8];
        #pragma unroll
        for (int j = 0; j < 8; ++j) xr0[j] = *(const float4*)(xgp + (size_t)j * 32 * HW);
        #pragma unroll
        for (int j = 0; j < 8; ++j) {
            xpk[j].x = cvt_pk_bf16(xr0[j].x, xr0[j].y);
            xpk[j].y = cvt_pk_bf16(xr0[j].z, xr0[j].w);
        }
    }

    v16f a00, a01, a10, a11;
    #pragma unroll
    for (int i = 0; i < 16; ++i) { a00[i] = 0.f; a01[i] = 0.f; a10[i] = 0.f; a11[i] = 0.f; }
    float racc = 0.f;

    #pragma unroll 1
    for (int mt = 0; mt < 64; ++mt) {
        const int cur = mt & 1;
        v16f s;
        #pragma unroll
        for (int i = 0; i < 16; ++i) s[i] = 0.f;
        #pragma unroll
        for (int ks = 0; ks < 4; ++ks)
            s = __builtin_amdgcn_mfma_f32_32x32x16_bf16(kf[ks], aq[ks], s, 0, 0, 0);
        const int mg = (mt < 63) ? (mt + 1) * 64 : 0;
        #pragma unroll
        for (int ks = 0; ks < 4; ++ks)
            kf[ks] = *(const v8s*)(kpt + (size_t)mg * 64 + ks * 16);
        float4 xr[8];
        if constexpr (!USEBF) {
            #pragma unroll
            for (int j = 0; j < 8; ++j)
                xr[j] = *(const float4*)(xgp + (size_t)j * 32 * HW + mg);
        }
        unsigned short* prow = plds + (size_t)(cur * PL_ROWS + nsub + l32) * LSTR + msub;
        #pragma unroll
        for (int rp = 0; rp < 8; ++rp) {
            const float e0 = __expf(s[2 * rp]);
            const float e1 = __expf(s[2 * rp + 1]);
            racc += e0 + e1;
            const int m0 = ((2 * rp) & 3) + 8 * (rp >> 1) + 4 * h;
            *(unsigned*)&prow[m0] = cvt_pk_bf16(e0, e1);
        }
        {
            unsigned short* xw = xp + (size_t)(cur * 256 + r0i) * LSTR + m4;
            #pragma unroll
            for (int j = 0; j < 8; ++j)
                *(uint2*)(xw + (size_t)j * 32 * LSTR) = xpk[j];
        }
        if constexpr (USEBF) {
            #pragma unroll
            for (int j = 0; j < 8; ++j)
                xpk[j] = *(const uint2*)(xbp + (size_t)j * 32 * HW + mg);
        }
        __syncthreads();
        {
            const unsigned short* xb0 = xp + (size_t)(cur * 256 + cs * 64 + l32) * LSTR;
            const unsigned short* xb1 = xb0 + (size_t)32 * LSTR;
            const unsigned short* pb0 = plds + (size_t)(cur * PL_ROWS + nh * 64 + l32) * LSTR;
            const unsigned short* pb1 = pb0 + (size_t)32 * LSTR;
            #pragma unroll
            for (int ks = 0; ks < 4; ++ks) {
                const int mo = ks * 16 + koff;
                const v8s xa0 = *(const v8s*)(xb0 + mo);
                const v8s xa1 = *(const v8s*)(xb1 + mo);
                const v8s pf0 = *(const v8s*)(pb0 + mo);
                const v8s pf1 = *(const v8s*)(pb1 + mo);
                a00 = __builtin_amdgcn_mfma_f32_32x32x16_bf16(xa0, pf0, a00, 0, 0, 0);
                a01 = __builtin_amdgcn_mfma_f32_32x32x16_bf16(xa0, pf1, a01, 0, 0, 0);
                a10 = __builtin_amdgcn_mfma_f32_32x32x16_bf16(xa1, pf0, a10, 0, 0, 0);
                a11 = __builtin_amdgcn_mfma_f32_32x32x16_bf16(xa1, pf1, a11, 0, 0, 0);
            }
        }
        if constexpr (!USEBF) {
            #pragma unroll
            for (int j = 0; j < 8; ++j) {
                xpk[j].x = cvt_pk_bf16(xr[j].x, xr[j].y);
                xpk[j].y = cvt_pk_bf16(xr[j].z, xr[j].w);
            }
        }
    }
    __syncthreads();
    {
        const float rtot = racc + __shfl_xor(racc, 32);
        if (lane < 32) rsums[nsub + l32][w & 1] = rtot;
    }
    __syncthreads();
    if (t < 128) lfin[t] = 1.0f / (rsums[t][0] + rsums[t][1]);
    __syncthreads();
    const float dn0 = lfin[nh * 64 + l32];
    const float dn1 = lfin[nh * 64 + 32 + l32];
    unsigned short (*zt)[ZSTR] = (unsigned short (*)[ZSTR])smem;
    #pragma unroll
    for (int rp = 0; rp < 8; ++rp) {
        const int r = rp * 2;
        const int c = cs * 64 + (r & 3) + 8 * (r >> 2) + 4 * h;
        const int n0r = nh * 64 + l32, n1r = nh * 64 + 32 + l32;
        *(unsigned*)&zt[n0r][c]      = cvt_pk_bf16(a00[r] * dn0, a00[r + 1] * dn0);
        *(unsigned*)&zt[n1r][c]      = cvt_pk_bf16(a01[r] * dn1, a01[r + 1] * dn1);
        *(unsigned*)&zt[n0r][c + 32] = cvt_pk_bf16(a10[r] * dn0, a10[r + 1] * dn0);
        *(unsigned*)&zt[n1r][c + 32] = cvt_pk_bf16(a11[r] * dn1, a11[r + 1] * dn1);
    }
    __syncthreads();
    const unsigned short* wvb = wvbf + (size_t)br * 65536;
    const float* bvp = br ? bv2 : bv1;
    const float gamma = gamma_p[0];
    const int ob = cs * 64;
    const int ncol = qt * 128 + nh * 64;
    v16f m00, m01, m10, m11;
    #pragma unroll
    for (int i = 0; i < 16; ++i) { m00[i] = 0.f; m01[i] = 0.f; m10[i] = 0.f; m11[i] = 0.f; }
    #pragma unroll
    for (int ks = 0; ks < 16; ++ks) {
        const int k = ks * 16 + koff;
        const v8s aA = *(const v8s*)(wvb + (size_t)(ob + l32) * 256 + k);
        const v8s aB = *(const v8s*)(wvb + (size_t)(ob + 32 + l32) * 256 + k);
        const v8s b0v = *(const v8s*)&zt[nh * 64 + l32][k];
        const v8s b1v = *(const v8s*)&zt[nh * 64 + 32 + l32][k];
        m00 = __builtin_amdgcn_mfma_f32_32x32x16_bf16(aA, b0v, m00, 0, 0, 0);
        m01 = __builtin_amdgcn_mfma_f32_32x32x16_bf16(aA, b1v, m01, 0, 0, 0);
        m10 = __builtin_amdgcn_mfma_f32_32x32x16_bf16(aB, b0v, m10, 0, 0, 0);
        m11 = __builtin_amdgcn_mfma_f32_32x32x16_bf16(aB, b1v, m11, 0, 0, 0);
    }
    #pragma unroll
    for (int r = 0; r < 16; ++r) {
        const int o = ob + (r & 3) + 8 * (r >> 2) + 4 * h;
        const float bvA = bvp[o], bvB = bvp[o + 32];
        const size_t base0 = (size_t)o * HW + ncol;
        const size_t base1 = (size_t)(o + 32) * HW + ncol;
        zo[base0 + l32]      = gamma * (m00[r] + bvA) + xg[base0 + l32];
        zo[base0 + 32 + l32] = gamma * (m01[r] + bvA) + xg[base0 + 32 + l32];
        zo[base1 + l32]      = gamma * (m10[r] + bvB) + xg[base1 + l32];
        zo[base1 + 32 + l32] = gamma * (m11[r] + bvB) + xg[base1 + 32 + l32];
    }
}

// ---------------- cpy_pad: out1/out2 f32 -> padded bf16 [b][chunk][66][66][ci16] ----------------
// (verified R11) Block = one (b, chunk, hp) row. hp 0/65 -> zeros; else transpose [16 ci][64 ww].
__global__ __launch_bounds__(256) void cpy_pad(const float* __restrict__ dsrc,
                                               unsigned short* __restrict__ cpy) {
    __shared__ float xls[16][65];
    const int hp = blockIdx.x, chunk = blockIdx.y, b = blockIdx.z;
    const int t = threadIdx.x;
    unsigned short* crow = cpy + (((size_t)(b * 32 + chunk) * 66 + hp) * 66) * 16;
    if (hp == 0 || hp == 65) {
        if (t < 132) *(uint4*)(crow + t * 8) = make_uint4(0, 0, 0, 0);
        return;
    }
    const int hh = hp - 1;
    const float* src = dsrc + O1_OFF + (size_t)(chunk < 16 ? 0 : 1) * 4194304
                     + (size_t)b * 1048576 + (size_t)((chunk & 15) * 16) * HW + (size_t)hh * 64;
    {
        const int ci = t >> 6, ww = t & 63;
        #pragma unroll
        for (int j = 0; j < 4; ++j)
            xls[ci + 4 * j][ww] = src[(size_t)(ci + 4 * j) * HW + ww];
    }
    __syncthreads();
    {
        const int wwp = t >> 2, q = t & 3;
        uint2 pk;
        pk.x = cvt_pk_bf16(xls[q * 4 + 0][wwp], xls[q * 4 + 1][wwp]);
        pk.y = cvt_pk_bf16(xls[q * 4 + 2][wwp], xls[q * 4 + 3][wwp]);
        *(uint2*)(crow + (size_t)(wwp + 1) * 16 + q * 4) = pk;
    }
    if (t < 4) {
        unsigned short* p = crow + (size_t)(t >> 1) * 65 * 16 + (t & 1) * 8;
        *(uint4*)p = make_uint4(0, 0, 0, 0);
    }
}

// ---------------- conv_v6: v3 structure, x staged from padded bf16 cpy ----------------
// ONLY delta vs v3 (measured best): x-staging = ~4 coalesced uint2 loads/thread-chunk
// from cpy (no predication, no cvt) -> same CPAD=20 conflict-free LDS layout.
// Weights, MFMA phase, grid(512)+XCD swizzle, epilogue: byte-identical to v3.
__global__ __launch_bounds__(256) void conv_v6(
    const unsigned short* __restrict__ wt,
    const unsigned short* __restrict__ cpy,
    const float* __restrict__ bn_scale, const float* __restrict__ bn_bias,
    const float* __restrict__ bn_mean,  const float* __restrict__ bn_var,
    float* __restrict__ dout) {
    __shared__ __align__(16) unsigned short xl[2][4][66][CPAD];   // 21,120 B
    __shared__ __align__(16) unsigned short wl[2][9][64][CPAD];   // 46,080 B

    const int bid = blockIdx.x;                      // 0..511
    const int xcd = bid & 7, j = bid >> 3;
    const int G   = xcd * 16 + (j >> 2);             // 0..127 = (pt,b)
    const int ot  = j & 3;
    const int pt  = G & 31;
    const int b   = G >> 5;
    const int h0 = pt * 2;
    const int t  = threadIdx.x;
    const int w  = t >> 6, lane = t & 63, h = lane >> 5, l32 = lane & 31;
    const int osub = (w & 1) * 32;
    const int ps0  = (w >> 1) * 64;

    // x slab: padded rows h0..h0+3 of (b,chunk): contiguous 4224 shorts = 1056 uint2
    const unsigned short* cb = cpy + (size_t)b * CPYB + (size_t)h0 * 66 * 16;
    // uint2 unit u -> pixel p=u>>2 (ci-quad q=u&3); LDS short off p*CPAD + q*4 (8B-aligned)
    unsigned short* xlf = &xl[0][0][0][0];

    float inv[16], add[16];
    #pragma unroll
    for (int r = 0; r < 16; ++r) {
        const int o_g = ot * 64 + osub + (r & 3) + 8 * (r >> 2) + 4 * h;
        const float iv = bn_scale[o_g] * __frsqrt_rn(bn_var[o_g] + 1e-5f);
        inv[r] = iv;
        add[r] = bn_bias[o_g] - bn_mean[o_g] * iv;
    }

    v16f acc0, acc1;
    #pragma unroll
    for (int i = 0; i < 16; ++i) { acc0[i] = 0.f; acc1[i] = 0.f; }

    const unsigned short* wbase = wt + (size_t)(ot * 64) * 16;

    // ---- prologue: chunk 0 into registers ----
    uint2 xs[5]; bool xv[5];
    uint2 wr[9];
    #pragma unroll
    for (int k = 0; k < 5; ++k) {
        const int u = t + k * 256;
        xv[k] = u < 1056;
        if (xv[k]) xs[k] = *(const uint2*)(cb + (size_t)u * 4);
    }
    #pragma unroll
    for (int u9 = 0; u9 < 9; ++u9) {
        const int u = t + u9 * 256;
        const int tap = u >> 8, rem2 = u & 255;
        const int o = rem2 >> 2, q = rem2 & 3;
        wr[u9] = *(const uint2*)(wbase + ((size_t)tap * 256 + o) * 16 + q * 4);
    }

    #pragma unroll 1
    for (int chunk = 0; chunk < 32; ++chunk) {
        const int cur = chunk & 1;
        // ---- write staged registers to LDS[cur] ----
        #pragma unroll
        for (int k = 0; k < 5; ++k) {
            if (xv[k]) {
                const int u = t + k * 256;
                const int p = u >> 2, q = u & 3;
                *(uint2*)&xlf[cur * XLHALF + p * CPAD + q * 4] = xs[k];
            }
        }
        #pragma unroll
        for (int u9 = 0; u9 < 9; ++u9) {
            const int u = t + u9 * 256;
            const int tap = u >> 8, rem2 = u & 255;
            const int o = rem2 >> 2, q = rem2 & 3;
            *(uint2*)&wl[cur][tap][o][q * 4] = wr[u9];
        }
        // ---- prefetch chunk+1 into registers ----
        if (chunk < 31) {
            const unsigned short* cn = cb + (size_t)(chunk + 1) * CPYCH;
            #pragma unroll
            for (int k = 0; k < 5; ++k)
                if (xv[k]) xs[k] = *(const uint2*)(cn + (size_t)(t + k * 256) * 4);
            const unsigned short* wsl = wbase + (size_t)(chunk + 1) * 36864;
            #pragma unroll
            for (int u9 = 0; u9 < 9; ++u9) {
                const int u = t + u9 * 256;
                const int tap = u >> 8, rem2 = u & 255;
                const int o = rem2 >> 2, q = rem2 & 3;
                wr[u9] = *(const uint2*)(wsl + ((size_t)tap * 256 + o) * 16 + q * 4);
            }
        }
        __syncthreads();         // LDS[cur] visible; chunk-2 reads of LDS[cur] drained
        // ---- MFMA on LDS[cur] (identical to v3) ----
        #pragma unroll
        for (int dy = 0; dy < 3; ++dy) {
            #pragma unroll
            for (int dx = 0; dx < 3; ++dx) {
                const v8s af = load8(&wl[cur][dy * 3 + dx][osub + l32][h * 8]);
                const int n0 = ps0 + l32, n1 = ps0 + 32 + l32;
                const v8s b0 = load8(&xl[cur][(n0 >> 6) + dy][(n0 & 63) + dx][h * 8]);
                const v8s b1 = load8(&xl[cur][(n1 >> 6) + dy][(n1 & 63) + dx][h * 8]);
                acc0 = __builtin_amdgcn_mfma_f32_32x32x16_bf16(af, b0, acc0, 0, 0, 0);
                acc1 = __builtin_amdgcn_mfma_f32_32x32x16_bf16(af, b1, acc1, 0, 0, 0);
            }
        }
    }
    const int px0 = ps0 + l32, px1 = ps0 + 32 + l32;
    const size_t gpx0 = (size_t)(h0 + (px0 >> 6)) * 64 + (px0 & 63);
    const size_t gpx1 = (size_t)(h0 + (px1 >> 6)) * 64 + (px1 & 63);
    #pragma unroll
    for (int r = 0; r < 16; ++r) {
        const int o_g = ot * 64 + osub + (r & 3) + 8 * (r >> 2) + 4 * h;
        const size_t obase = ((size_t)b * 256 + o_g) * HW;
        float v0 = acc0[r] * inv[r] + add[r];
        float v1 = acc1[r] * inv[r] + add[r];
        v0 = v0 > 0.f ? v0 : 0.f;
        v1 = v1 > 0.f ? v1 : 0.f;
        dout[obase + gpx0] = v0;
        dout[obase + gpx1] = v1;
    }
}

// ---------------- conv v3 fallback (unchanged, for small ws) ----------------
__global__ __launch_bounds__(256) void conv_kernel(
    const unsigned short* __restrict__ wt,
    const float* __restrict__ bn_scale, const float* __restrict__ bn_bias,
    const float* __restrict__ bn_mean,  const float* __restrict__ bn_var,
    float* __restrict__ dout) {
    __shared__ __align__(16) unsigned short xl[2][4][66][CPAD];
    __shared__ __align__(16) unsigned short wl[2][9][64][CPAD];

    const int bid = blockIdx.x;
    const int xcd = bid & 7, j = bid >> 3;
    const int G   = xcd * 16 + (j >> 2);
    const int ot  = j & 3;
    const int pt  = G & 31;
    const int b   = G >> 5;
    const int h0 = pt * 2;
    const int t  = threadIdx.x;
    const int w  = t >> 6, lane = t & 63, h = lane >> 5, l32 = lane & 31;
    const int osub = (w & 1) * 32;
    const int ps0  = (w >> 1) * 64;

    int ldsoff[9], srcoff[9]; bool valid[9], inb[9];
    #pragma unroll
    for (int k = 0; k < 9; ++k) {
        const int i = t + k * 256;
        valid[k] = i < 2112;
        const int col = i % 66, rem = i / 66;
        const int row = rem & 3, cp = rem >> 2;
        const int hh = h0 + row - 1, ww = col - 1;
        inb[k] = (hh >= 0 && hh < 64 && ww >= 0 && ww < 64);
        srcoff[k] = 2 * cp * HW + (inb[k] ? hh * 64 + ww : 0);
        ldsoff[k] = (row * 66 + col) * CPAD + 2 * cp;
    }
    unsigned short* xlf = &xl[0][0][0][0];

    float inv[16], add[16];
    #pragma unroll
    for (int r = 0; r < 16; ++r) {
        const int o_g = ot * 64 + osub + (r & 3) + 8 * (r >> 2) + 4 * h;
        const float iv = bn_scale[o_g] * __frsqrt_rn(bn_var[o_g] + 1e-5f);
        inv[r] = iv;
        add[r] = bn_bias[o_g] - bn_mean[o_g] * iv;
    }

    v16f acc0, acc1;
    #pragma unroll
    for (int i = 0; i < 16; ++i) { acc0[i] = 0.f; acc1[i] = 0.f; }

    const float* bsrc = dout + O1_OFF + (size_t)b * 1048576;
    const unsigned short* wbase = wt + (size_t)(ot * 64) * 16;

    float xv0[9], xv1[9];
    uint2 wr[9];
    {
        const float* src = bsrc;
        #pragma unroll
        for (int k = 0; k < 9; ++k) {
            xv0[k] = 0.f; xv1[k] = 0.f;
            if (valid[k] && inb[k]) {
                const float* p = src + srcoff[k];
                xv0[k] = p[0]; xv1[k] = p[HW];
            }
        }
        #pragma unroll
        for (int u9 = 0; u9 < 9; ++u9) {
            const int u = t + u9 * 256;
            const int tap = u >> 8, rem2 = u & 255;
            const int o = rem2 >> 2, q = rem2 & 3;
            wr[u9] = *(const uint2*)(wbase + ((size_t)tap * 256 + o) * 16 + q * 4);
        }
    }

    #pragma unroll 1
    for (int chunk = 0; chunk < 32; ++chunk) {
        const int cur = chunk & 1;
        #pragma unroll
        for (int k = 0; k < 9; ++k)
            if (valid[k])
                *(unsigned*)&xlf[cur * XLHALF + ldsoff[k]] = cvt_pk_bf16(xv0[k], xv1[k]);
        #pragma unroll
        for (int u9 = 0; u9 < 9; ++u9) {
            const int u = t + u9 * 256;
            const int tap = u >> 8, rem2 = u & 255;
            const int o = rem2 >> 2, q = rem2 & 3;
            *(uint2*)&wl[cur][tap][o][q * 4] = wr[u9];
        }
        if (chunk < 31) {
            const int cn = chunk + 1;
            const float* src = bsrc + (size_t)(cn < 16 ? 0 : 1) * 4194304
                             + (size_t)((cn & 15) * 16) * HW;
            #pragma unroll
            for (int k = 0; k < 9; ++k) {
                xv0[k] = 0.f; xv1[k] = 0.f;
                if (valid[k] && inb[k]) {
                    const float* p = src + srcoff[k];
                    xv0[k] = p[0]; xv1[k] = p[HW];
                }
            }
            const unsigned short* wsl = wbase + (size_t)cn * 36864;
            #pragma unroll
            for (int u9 = 0; u9 < 9; ++u9) {
                const int u = t + u9 * 256;
                const int tap = u >> 8, rem2 = u & 255;
                const int o = rem2 >> 2, q = rem2 & 3;
                wr[u9] = *(const uint2*)(wsl + ((size_t)tap * 256 + o) * 16 + q * 4);
            }
        }
        __syncthreads();
        #pragma unroll
        for (int dy = 0; dy < 3; ++dy) {
            #pragma unroll
            for (int dx = 0; dx < 3; ++dx) {
                const v8s af = load8(&wl[cur][dy * 3 + dx][osub + l32][h * 8]);
                const int n0 = ps0 + l32, n1 = ps0 + 32 + l32;
                const v8s b0 = load8(&xl[cur][(n0 >> 6) + dy][(n0 & 63) + dx][h * 8]);
                const v8s b1 = load8(&xl[cur][(n1 >> 6) + dy][(n1 & 63) + dx][h * 8]);
                acc0 = __builtin_amdgcn_mfma_f32_32x32x16_bf16(af, b0, acc0, 0, 0, 0);
                acc1 = __builtin_amdgcn_mfma_f32_32x32x16_bf16(af, b1, acc1, 0, 0, 0);
            }
        }
    }
    const int px0 = ps0 + l32, px1 = ps0 + 32 + l32;
    const size_t gpx0 = (size_t)(h0 + (px0 >> 6)) * 64 + (px0 & 63);
    const size_t gpx1 = (size_t)(h0 + (px1 >> 6)) * 64 + (px1 & 63);
    #pragma unroll
    for (int r = 0; r < 16; ++r) {
        const int o_g = ot * 64 + osub + (r & 3) + 8 * (r >> 2) + 4 * h;
        const size_t obase = ((size_t)b * 256 + o_g) * HW;
        float v0 = acc0[r] * inv[r] + add[r];
        float v1 = acc1[r] * inv[r] + add[r];
        v0 = v0 > 0.f ? v0 : 0.f;
        v1 = v1 > 0.f ? v1 : 0.f;
        dout[obase + gpx0] = v0;
        dout[obase + gpx1] = v1;
    }
}

extern "C" void kernel_launch(void* const* d_in, const int* in_sizes, int n_in,
                              void* d_out, int out_size, void* d_ws, size_t ws_size,
                              hipStream_t stream) {
    (void)in_sizes; (void)n_in; (void)out_size;
    const float* x1   = (const float*)d_in[0];
    const float* x2   = (const float*)d_in[1];
    const float* wq1  = (const float*)d_in[2];
    const float* bq1  = (const float*)d_in[3];
    const float* wk1  = (const float*)d_in[4];
    const float* bk1  = (const float*)d_in[5];
    const float* wv1  = (const float*)d_in[6];
    const float* bv1  = (const float*)d_in[7];
    const float* wq2  = (const float*)d_in[8];
    const float* bq2  = (const float*)d_in[9];
    const float* wk2  = (const float*)d_in[10];
    const float* bk2  = (const float*)d_in[11];
    const float* wv2  = (const float*)d_in[12];
    const float* bv2  = (const float*)d_in[13];
    const float* gma  = (const float*)d_in[14];
    const float* wcat = (const float*)d_in[15];
    const float* bns  = (const float*)d_in[16];
    const float* bnb  = (const float*)d_in[17];
    const float* bnm  = (const float*)d_in[18];
    const float* bnv  = (const float*)d_in[19];

    float* out = (float*)d_out;
    unsigned short* wtc = (unsigned short*)d_ws;
    unsigned short* wvb = wtc + WVB_OFF;
    unsigned short* xbf = wtc + XBF_OFF;             // xbf; cpy overlays it post-attn
    const bool use_bf  = ws_size >= WS_NEED;
    const bool use_cvb = ws_size >= WS_NEED2;        // implies use_bf

    wprep_proj<<<704, 256, 0, stream>>>(wq1, wk1, wv1, wq2, wk2, wv2, out + WTP_OFF);
    wprep_convw<<<4608, 256, 0, stream>>>(wcat, wtc);
    wprep_wv<<<512, 256, 0, stream>>>(wv1, wv2, wvb);
    if (use_bf) wprep_xbf<<<4096, 256, 0, stream>>>(x1, x2, xbf);
    proj_kernel<<<dim3(64, 2, 4), 256, 0, stream>>>(x1, x2, bq1, bk1, bq2, bk2, out);
    if (use_bf)
        attn_kernel<1><<<256, 512, 0, stream>>>(x1, x2, xbf, wvb, bv1, bv2, gma, out);
    else
        attn_kernel<0><<<256, 512, 0, stream>>>(x1, x2, xbf, wvb, bv1, bv2, gma, out);
    if (use_cvb) {
        cpy_pad<<<dim3(66, 32, 4), 256, 0, stream>>>(out, xbf);
        conv_v6<<<512, 256, 0, stream>>>(wtc, xbf, bns, bnb, bnm, bnv, out);
    } else {
        conv_kernel<<<512, 256, 0, stream>>>(wtc, bns, bnb, bnm, bnv, out);
    }
}